// Round 6
// baseline (273.723 us; speedup 1.0000x reference)
//
#include <hip/hip_runtime.h>
#include <stdint.h>

#define N_ROWS  8192   // B*S = 4*2048
#define DIM     256
#define K_CODES 8192
#define SPLITK  16
#define KS      512           // codes per split
#define NT      128           // codes per K-tile
#define LSLOTS  16            // per-row append slots in LDS
#define GSLOTS  8             // per-row-split survivor slots in ws
// acc-space (dot) margin: covers dist-bucket/2 (1.5e-5) + 2*bf16 dot err max
// (~4.5e-5) + dropped cnorm/2 (1.9e-6). 1e-4 leaves ~1.6x slack.
#define MARGIN_ACC 1.0e-4f

typedef unsigned long long u64;
typedef unsigned short u16;
typedef short s16x8 __attribute__((ext_vector_type(8)));   // 8 bf16 = 4 VGPR
typedef float f32x4 __attribute__((ext_vector_type(4)));

__device__ __forceinline__ u64 u64min(u64 a, u64 b) { return a < b ? a : b; }

// float -> bf16 bits, round-to-nearest-even (no NaN inputs here)
__device__ __forceinline__ u16 f2bf(float f) {
    unsigned u = __float_as_uint(f);
    u += 0x7fffu + ((u >> 16) & 1u);
    return (u16)(u >> 16);
}

// ---------------------------------------------------------------- kernel A
// Fused: bf16 conversion of z_e & cb + row norms. One wave per row.
__global__ __launch_bounds__(256) void vq_prep(const float* __restrict__ z_e,
                                               const float* __restrict__ cb,
                                               u16* __restrict__ zb,
                                               u16* __restrict__ cbb,
                                               float* __restrict__ xnorm,
                                               float* __restrict__ cnorm) {
    int wid  = (blockIdx.x * 256 + threadIdx.x) >> 6;
    int lane = threadIdx.x & 63;
    const float* src; u16* d16; float* dn;
    if (wid < N_ROWS) { src = z_e + (size_t)wid * DIM; d16 = zb + (size_t)wid * DIM; dn = xnorm + wid; }
    else              { int k = wid - N_ROWS;
                        src = cb  + (size_t)k   * DIM; d16 = cbb + (size_t)k * DIM; dn = cnorm + k; }
    float4 v = *(const float4*)(src + lane * 4);
    ushort4 h;
    h.x = f2bf(v.x); h.y = f2bf(v.y); h.z = f2bf(v.z); h.w = f2bf(v.w);
    *(ushort4*)(d16 + lane * 4) = h;
    float s = (v.x * v.x + v.y * v.y) + (v.z * v.z + v.w * v.w);
#pragma unroll
    for (int off = 1; off < 64; off <<= 1)
        s += __shfl_xor(s, off, 64);
    if (lane == 0) *dn = s;
}

// ---------------------------------------------------------------- kernel B
// bf16 MFMA dot GEMM + per-row running MAX of dot (argmin dist == argmax dot;
// xnorm constant per row, cnorm<=3.8e-6 folded into margin) + margin-append.
// Block: 128 rows x 512 codes (one split), 4 waves, each a 32-row slab.
//
// R6 restructure: NO LDS STAGING, NO K-LOOP BARRIERS. The split's codebook
// slice is 256 KB and L2-resident by construction (XCD-pinned: linear%8 ==
// split%8, <=0.5 MB per XCD L2) -- staging L2-fit data through LDS was pure
// overhead (3 rounds of vmcnt/barrier pipelines all sat at 14-20% MfmaUtil,
// latency/barrier-bound, and R3/R4 showed the apparatus is race-prone).
// B-fragments load DIRECTLY from global: lane (quad,l16) of frag j reads
// 16B at cbb[(cb0+j*16+l16)*DIM + s*32+quad*8] -> one inst = 16 rows x 64B
// = 16 full cache lines, 100% utilized, L1/L2-hit. Intra-block 4-wave
// redundancy is absorbed by L1 (per-64-code-group working set = 32 KB = L1).
// Codes processed in two 64-code groups per kt so acc[2][4]=32 VGPR;
// total ~145 VGPR -> 3 waves/SIMD (12 waves/CU) via __launch_bounds__(256,3).
// Only 2 plain __syncthreads() remain (around the candidate filter).
__global__ __launch_bounds__(256, 3) void vq_mfma(const u16* __restrict__ zb,
                                                  const u16* __restrict__ cbb,
                                                  int* __restrict__ cand_cnt,
                                                  int* __restrict__ cand_idx) {
    __shared__ float lcd[128 * LSLOTS];   // 8 KB
    __shared__ int   lci[128 * LSLOTS];   // 8 KB
    __shared__ int   lcnt[128];
    __shared__ float gmaxs[128];

    const int tid   = threadIdx.x;
    const int lane  = tid & 63;
    const int wave  = tid >> 6;
    const int quad  = lane >> 4;
    const int l16   = lane & 15;
    const int split = blockIdx.x;
    const int n0    = blockIdx.y * 128;

    if (tid < 128) lcnt[tid] = 0;

    // ---- A fragments in registers. af[i][s]: row n0+wave*32+i*16+l16,
    // dims s*32 + quad*8 .. +7
    s16x8 af[2][8];
#pragma unroll
    for (int i = 0; i < 2; i++) {
        const u16* p = zb + (size_t)(n0 + wave * 32 + i * 16 + l16) * DIM + quad * 8;
#pragma unroll
        for (int s = 0; s < 8; s++)
            af[i][s] = *(const s16x8*)(p + s * 32);
    }

    __syncthreads();   // lcnt init visible to all waves before first append

    float runmax[8];
#pragma unroll
    for (int t = 0; t < 8; t++) runmax[t] = -3.0e38f;

    for (int kt = 0; kt < KS / NT; kt++) {      // 4 K-tiles of 128 codes
        const int kbase = split * KS + kt * NT;
#pragma unroll
        for (int jg = 0; jg < 2; jg++) {        // two 64-code groups
            const int cb0 = kbase + jg * 64;
            // row pointers for the 4 code-frags of this group
            const u16* rp0 = cbb + (size_t)(cb0 + l16) * DIM + quad * 8;
            const u16* rp1 = rp0 + 16 * DIM;
            const u16* rp2 = rp0 + 32 * DIM;
            const u16* rp3 = rp0 + 48 * DIM;

            f32x4 acc[2][4];
#pragma unroll
            for (int i = 0; i < 2; i++)
#pragma unroll
                for (int j = 0; j < 4; j++)
#pragma unroll
                    for (int e = 0; e < 4; e++) acc[i][j][e] = 0.0f;

#pragma unroll
            for (int s = 0; s < 8; s++) {       // K = 8 x 32
                s16x8 b0 = *(const s16x8*)(rp0 + s * 32);
                s16x8 b1 = *(const s16x8*)(rp1 + s * 32);
                s16x8 b2 = *(const s16x8*)(rp2 + s * 32);
                s16x8 b3 = *(const s16x8*)(rp3 + s * 32);
#pragma unroll
                for (int i = 0; i < 2; i++) {
                    acc[i][0] = __builtin_amdgcn_mfma_f32_16x16x32_bf16(af[i][s], b0, acc[i][0], 0, 0, 0);
                    acc[i][1] = __builtin_amdgcn_mfma_f32_16x16x32_bf16(af[i][s], b1, acc[i][1], 0, 0, 0);
                    acc[i][2] = __builtin_amdgcn_mfma_f32_16x16x32_bf16(af[i][s], b2, acc[i][2], 0, 0, 0);
                    acc[i][3] = __builtin_amdgcn_mfma_f32_16x16x32_bf16(af[i][s], b3, acc[i][3], 0, 0, 0);
                }
            }

            // ---- epilogue for this 64-code group: in-wave row max,
            // runmax update, margin appends. Row rl = wave*32+i*16+quad*4+r
            // (wave-owned; appends race only within the wave -> LDS atomics).
#pragma unroll
            for (int i = 0; i < 2; i++)
#pragma unroll
                for (int r = 0; r < 4; r++) {
                    float m = fmaxf(fmaxf(acc[i][0][r], acc[i][1][r]),
                                    fmaxf(acc[i][2][r], acc[i][3][r]));
                    m = fmaxf(m, __shfl_xor(m, 1, 64));
                    m = fmaxf(m, __shfl_xor(m, 2, 64));
                    m = fmaxf(m, __shfl_xor(m, 4, 64));
                    m = fmaxf(m, __shfl_xor(m, 8, 64));
                    runmax[i * 4 + r] = fmaxf(runmax[i * 4 + r], m);
                    float thr = runmax[i * 4 + r] - MARGIN_ACC;
                    int rl = wave * 32 + i * 16 + quad * 4 + r;
#pragma unroll
                    for (int j = 0; j < 4; j++) {
                        float d = acc[i][j][r];
                        if (d >= thr) {
                            int pos = atomicAdd(&lcnt[rl], 1);
                            if (pos < LSLOTS) {
                                lcd[rl * LSLOTS + pos] = d;
                                lci[rl * LSLOTS + pos] = cb0 + j * 16 + l16;
                            }
                        }
                    }
                }
        }
    }

    if (l16 == 0) {
#pragma unroll
        for (int i = 0; i < 2; i++)
#pragma unroll
            for (int r = 0; r < 4; r++)
                gmaxs[wave * 32 + i * 16 + quad * 4 + r] = runmax[i * 4 + r];
    }
    __syncthreads();

    // filter appends vs final row max (winner guaranteed in the superset).
    // cand layout transposed to [split][n]: each block writes a contiguous
    // private range (R5's [n][split] layout caused ~8 MB of dirty-line
    // writebacks -- one 64B line shared by 16 blocks).
    if (tid < 128) {
        int n   = n0 + tid;
        int cnt = lcnt[tid]; if (cnt > LSLOTS) cnt = LSLOTS;
        float thrf = gmaxs[tid] - MARGIN_ACC;
        int base = (split * N_ROWS + n) * GSLOTS;
        int w = 0;
        for (int s = 0; s < cnt && w < GSLOTS; s++)
            if (lcd[tid * LSLOTS + s] >= thrf)
                cand_idx[base + w++] = lci[tid * LSLOTS + s];
        cand_cnt[split * N_ROWS + n] = w;
    }
}

// ---------------------------------------------------------------- kernel C
// Exact fp32 recheck (association identical to the passing version:
// sequential fmaf d=0..255, fmaf(-2,m,xn)+cn), lexicographic (dist,idx) min;
// then gather + z_q_st + rowloss. One wave per row.
__global__ __launch_bounds__(256) void vq_finalize(const float* __restrict__ z_e,
                                                   const float* __restrict__ cb,
                                                   const float* __restrict__ xnorm,
                                                   const float* __restrict__ cnorm,
                                                   const int* __restrict__ cand_cnt,
                                                   const int* __restrict__ cand_idx,
                                                   float* __restrict__ out_zq,
                                                   float* __restrict__ out_idx,
                                                   float* __restrict__ rowloss) {
    const int n    = blockIdx.x * 4 + (threadIdx.x >> 6);
    const int lane = threadIdx.x & 63;

    int myidx = -1;
    int t = 0;
#pragma unroll
    for (int s = 0; s < SPLITK; s++) {
        int c = cand_cnt[s * N_ROWS + n];
        if (lane >= t && lane < t + c)
            myidx = cand_idx[(s * N_ROWS + n) * GSLOTS + (lane - t)];
        t += c;
    }

    u64 key = ~0ULL;
    if (myidx >= 0) {
        const float* xr = z_e + (size_t)n * DIM;
        const float* cr = cb + (size_t)myidx * DIM;
        float acc = 0.0f;
#pragma unroll 8
        for (int d = 0; d < DIM; d++)
            acc = __builtin_fmaf(xr[d], cr[d], acc);
        float dist = __builtin_fmaf(-2.0f, acc, xnorm[n]) + cnorm[myidx];
        key = ((u64)__float_as_uint(dist) << 32) | (unsigned)myidx;
    }
#pragma unroll
    for (int off = 1; off < 64; off <<= 1)
        key = u64min(key, __shfl_xor(key, off, 64));

    int idx = (int)(unsigned)(key & 0xffffffffu);
    if (key == ~0ULL) idx = 0;  // unreachable safety

    float4 x = *(const float4*)(z_e + (size_t)n * DIM + lane * 4);
    float4 c = *(const float4*)(cb + (size_t)idx * DIM + lane * 4);
    float4 st;
    st.x = x.x + (c.x - x.x); st.y = x.y + (c.y - x.y);
    st.z = x.z + (c.z - x.z); st.w = x.w + (c.w - x.w);
    *(float4*)(out_zq + (size_t)n * DIM + lane * 4) = st;

    float d0 = x.x - c.x, d1 = x.y - c.y, d2 = x.z - c.z, d3 = x.w - c.w;
    float s2 = (d0 * d0 + d1 * d1) + (d2 * d2 + d3 * d3);
#pragma unroll
    for (int off = 1; off < 64; off <<= 1)
        s2 += __shfl_xor(s2, off, 64);
    if (lane == 0) {
        rowloss[n] = s2;
        out_idx[n] = (float)idx;
    }
}

// ---------------------------------------------------------------- kernel D
__global__ __launch_bounds__(256) void vq_loss(const float* __restrict__ rowloss,
                                               float* __restrict__ out_loss) {
    __shared__ double sd[256];
    double s = 0.0;
    for (int i = threadIdx.x; i < N_ROWS; i += 256) s += (double)rowloss[i];
    sd[threadIdx.x] = s;
    __syncthreads();
    for (int off = 128; off; off >>= 1) {
        if (threadIdx.x < off) sd[threadIdx.x] += sd[threadIdx.x + off];
        __syncthreads();
    }
    if (threadIdx.x == 0) {
        double mean = sd[0] / (double)((size_t)N_ROWS * DIM);
        out_loss[0] = (float)(1.25 * mean);
    }
}

// ---------------------------------------------------------------- launch
extern "C" void kernel_launch(void* const* d_in, const int* in_sizes, int n_in,
                              void* d_out, int out_size, void* d_ws, size_t ws_size,
                              hipStream_t stream) {
    const float* z_e = (const float*)d_in[0];
    const float* cb  = (const float*)d_in[1];

    float* out   = (float*)d_out;
    float* zq    = out;
    float* oidx  = out + (size_t)N_ROWS * DIM;
    float* oloss = oidx + N_ROWS;

    // ws layout (~12.6 MB):
    //   zb   bf16[8192*256]  4 MB
    //   cbb  bf16[8192*256]  4 MB
    //   xnorm/cnorm/rowloss  3*32 KB
    //   cand_cnt int[SPLITK*N_ROWS]        512 KB   ([split][n] layout)
    //   cand_idx int[SPLITK*N_ROWS*GSLOTS] 4 MB     ([split][n][slot])
    u16*   zb       = (u16*)d_ws;
    u16*   cbb      = zb + (size_t)N_ROWS * DIM;
    float* xnorm    = (float*)(cbb + (size_t)K_CODES * DIM);
    float* cnorm    = xnorm + N_ROWS;
    float* rowloss  = cnorm + K_CODES;
    int*   cand_cnt = (int*)(rowloss + N_ROWS);
    int*   cand_idx = cand_cnt + N_ROWS * SPLITK;

    vq_prep    <<<(N_ROWS + K_CODES) / 4, 256, 0, stream>>>(z_e, cb, zb, cbb, xnorm, cnorm);
    // grid (split, mtile): linear%8 == split%8 -> splits s and s+8 pinned to
    // one XCD; their 2x256KB bf16 codebook slices + zb rows stay L2-resident.
    vq_mfma    <<<dim3(SPLITK, N_ROWS / 128), 256, 0, stream>>>(zb, cbb, cand_cnt, cand_idx);
    vq_finalize<<<N_ROWS / 4, 256, 0, stream>>>(z_e, cb, xnorm, cnorm, cand_cnt, cand_idx, zq, oidx, rowloss);
    vq_loss    <<<1, 256, 0, stream>>>(rowloss, oloss);
}

// Round 7
// 212.165 us; speedup vs baseline: 1.2901x; 1.2901x over previous
//
#include <hip/hip_runtime.h>
#include <stdint.h>

#define N_ROWS  8192   // B*S = 4*2048
#define DIM     256
#define K_CODES 8192
#define SPLITK  16
#define KS      512           // codes per split
#define NT      64            // codes per K-tile (acc[2][4] = 32 AGPR)
#define LSLOTS  16            // per-row append slots in LDS
#define GSLOTS  8             // per-row-split survivor slots in ws
// acc-space (dot) margin: covers dist-bucket/2 (1.5e-5) + 2*bf16 dot err max
// (~4.5e-5) + dropped cnorm/2 (1.9e-6). 1e-4 leaves ~1.6x slack.
#define MARGIN_ACC 1.0e-4f

typedef unsigned long long u64;
typedef unsigned short u16;
typedef short s16x8 __attribute__((ext_vector_type(8)));   // 8 bf16 = 4 VGPR
typedef float f32x4 __attribute__((ext_vector_type(4)));

__device__ __forceinline__ u64 u64min(u64 a, u64 b) { return a < b ? a : b; }

// float -> bf16 bits, round-to-nearest-even (no NaN inputs here)
__device__ __forceinline__ u16 f2bf(float f) {
    unsigned u = __float_as_uint(f);
    u += 0x7fffu + ((u >> 16) & 1u);
    return (u16)(u >> 16);
}

// async 16B global->LDS (dest = wave-uniform base + lane*16, HW-added)
__device__ __forceinline__ void gld16(void* lds, const void* g) {
    __builtin_amdgcn_global_load_lds(
        (const __attribute__((address_space(1))) unsigned int*)g,
        (__attribute__((address_space(3))) unsigned int*)lds, 16, 0, 0);
}

// Raw s_barrier with compiler memory fences on BOTH sides (naked builtin
// does not order memory at the compiler level -> R3/R4 races).
__device__ __forceinline__ void block_barrier() {
    asm volatile("" ::: "memory");
    __builtin_amdgcn_s_barrier();
    asm volatile("" ::: "memory");
}

// ---------------------------------------------------------------- kernel A
// Fused: bf16 conversion of z_e & cb + row norms. One wave per row.
__global__ __launch_bounds__(256) void vq_prep(const float* __restrict__ z_e,
                                               const float* __restrict__ cb,
                                               u16* __restrict__ zb,
                                               u16* __restrict__ cbb,
                                               float* __restrict__ xnorm,
                                               float* __restrict__ cnorm) {
    int wid  = (blockIdx.x * 256 + threadIdx.x) >> 6;
    int lane = threadIdx.x & 63;
    const float* src; u16* d16; float* dn;
    if (wid < N_ROWS) { src = z_e + (size_t)wid * DIM; d16 = zb + (size_t)wid * DIM; dn = xnorm + wid; }
    else              { int k = wid - N_ROWS;
                        src = cb  + (size_t)k   * DIM; d16 = cbb + (size_t)k * DIM; dn = cnorm + k; }
    float4 v = *(const float4*)(src + lane * 4);
    ushort4 h;
    h.x = f2bf(v.x); h.y = f2bf(v.y); h.z = f2bf(v.z); h.w = f2bf(v.w);
    *(ushort4*)(d16 + lane * 4) = h;
    float s = (v.x * v.x + v.y * v.y) + (v.z * v.z + v.w * v.w);
#pragma unroll
    for (int off = 1; off < 64; off <<= 1)
        s += __shfl_xor(s, off, 64);
    if (lane == 0) *dn = s;
}

// ---------------------------------------------------------------- kernel B
// bf16 MFMA dot GEMM + per-row running MAX of dot (argmin dist == argmax dot;
// xnorm constant per row, cnorm<=3.8e-6 folded into margin) + margin-append.
// Block: 128 rows x 512 codes (one split), 4 waves, each a 32-row slab.
//
// R7 = R2's proven schedule shape at 3-waves/SIMD register budget:
//  * Evidence: R2 (64us) was reg-capped at 2 waves/SIMD -- af(64 VGPR) +
//    acc[2][8](64 AGPR) + ~110 VGPR side = 172-176 regs > 512/3 = 170.
//    R6's direct-global B (no LDS) was latency-bound (9% MfmaUtil): each
//    load gathers 16 scattered 64B lines with no in-flight reg capacity.
//  * NT=64 K-tiles: acc[2][4] = 32 AGPR (half of R2/R5) -> total ~140 regs
//    < 170 -> 3 waves/SIMD (12 waves/CU). SPLITK=16 supplies 16 waves/CU.
//    launch_bounds(256,2): NO forced cap -> no spill -> vmcnt count safe.
//  * C staged into 3-deep ring of 8 KB chunks (64 codes x 64 dims, 128B-row
//    XOR swizzle, 2-way-free banking), LDS 41 KB. 32 iters/block, each:
//      STAGE(it+2) -> 8x ds_read_b128 -> 16 MFMA [-> epilogue at kt end]
//      -> vmcnt(2) lgkmcnt(0) -> fenced barrier
//    vmcnt(2) drains stage(it+1) (FIFO: last 2 issued = stage(it+2));
//    2-iter prefetch cover (~400cyc) > L2 latency. Tail: vmcnt(0) at it=30.
//  * All R5 hardening kept: fenced barriers, lgkmcnt(0) runtime drain.
//  * R6's [split][n] candidate layout kept (WRITE 8.2 -> 4.6 MB).
__global__ __launch_bounds__(256, 2) void vq_mfma(const u16* __restrict__ zb,
                                                  const u16* __restrict__ cbb,
                                                  int* __restrict__ cand_cnt,
                                                  int* __restrict__ cand_idx) {
    __shared__ u16   Cs[3][64 * 64];   // 24 KB ring: 3 x (64 code-rows x 64 dims), swizzled
    __shared__ float lcd[128 * LSLOTS];   // 8 KB
    __shared__ int   lci[128 * LSLOTS];   // 8 KB
    __shared__ int   lcnt[128];
    __shared__ float gmaxs[128];

    const int tid   = threadIdx.x;
    const int lane  = tid & 63;
    const int wave  = tid >> 6;
    const int quad  = lane >> 4;
    const int l16   = lane & 15;
    const int split = blockIdx.x;
    const int n0    = blockIdx.y * 128;

    if (tid < 128) lcnt[tid] = 0;

    // staging lane constants: lane covers (row srow8 of 8-group, dest chunk schunk)
    const int srow8  = lane >> 3;
    const int schunk = lane & 7;
    const int ssw    = (schunk ^ srow8) * 8;   // swizzled source chunk offset (shorts)
    const u16* csrc  = cbb + (size_t)split * KS * DIM + (size_t)srow8 * DIM + ssw;

    // ---- A fragments in registers (issued FIRST: retire under the first
    // vmcnt(2) by FIFO order). af[i][s]: row n0+wave*32+i*16+l16,
    // dims s*32 + quad*8 .. +7
    s16x8 af[2][8];
#pragma unroll
    for (int i = 0; i < 2; i++) {
        const u16* p = zb + (size_t)(n0 + wave * 32 + i * 16 + l16) * DIM + quad * 8;
#pragma unroll
        for (int s = 0; s < 8; s++)
            af[i][s] = *(const s16x8*)(p + s * 32);
    }

    // stage chunk s (kt = s>>2 : 64-code tile; kc = s&3 : 64-dim chunk)
    // into ring slot. Per wave: 2 gld16 covering code-row-groups wave*2+t.
    auto STAGE = [&](int s, int slot) {
        const int kts = s >> 2, kcs = s & 3;
        const u16* src = csrc + (size_t)(kts * NT) * DIM + kcs * 64;
#pragma unroll
        for (int t = 0; t < 2; t++) {
            int rg = wave * 2 + t;            // 8-code-row group, wave-uniform
            gld16(&Cs[slot][rg * 512], src + (size_t)rg * (8 * DIM));
        }
    };

    f32x4 acc[2][4];
    float runmax[8];
#pragma unroll
    for (int t = 0; t < 8; t++) runmax[t] = -3.0e38f;

    // prologue: 2-ahead; vmcnt(2) drains af + stage(0), leaves stage(1).
    STAGE(0, 0); STAGE(1, 1);
    asm volatile("s_waitcnt vmcnt(2) lgkmcnt(0)" ::: "memory");
    block_barrier();

    for (int kt = 0; kt < KS / NT; kt++) {    // 8 tiles of 64 codes
        const int cb0 = split * KS + kt * NT;
#pragma unroll
        for (int i = 0; i < 2; i++)
#pragma unroll
            for (int j = 0; j < 4; j++)
#pragma unroll
                for (int e = 0; e < 4; e++) acc[i][j][e] = 0.0f;

#pragma unroll
        for (int kc = 0; kc < 4; kc++) {      // 64-dim chunks
            const int it = kt * 4 + kc;
            if (it < 30) STAGE(it + 2, (it + 2) % 3);   // 2-ahead prefetch

            const u16* cbuf = &Cs[it % 3][0];           // staged(it), published
#pragma unroll
            for (int ks = 0; ks < 2; ks++) {
                s16x8 bfr[4];
#pragma unroll
                for (int jj = 0; jj < 4; jj++)
                    bfr[jj] = *(const s16x8*)&cbuf[(jj * 16 + l16) * 64 +
                                                   (((ks << 2) | quad) ^ (l16 & 7)) * 8];
#pragma unroll
                for (int i = 0; i < 2; i++)
#pragma unroll
                    for (int jj = 0; jj < 4; jj++)
                        acc[i][jj] = __builtin_amdgcn_mfma_f32_16x16x32_bf16(
                            af[i][kc * 2 + ks], bfr[jj], acc[i][jj], 0, 0, 0);
            }

            // ---- epilogue at kt end, BEFORE the wait (overlaps stage latency):
            // in-wave row max over 4 code-frags, runmax update, margin appends.
            // Row rl = wave*32+i*16+quad*4+r (wave-owned; LDS atomics).
            if (kc == 3) {
#pragma unroll
                for (int i = 0; i < 2; i++)
#pragma unroll
                    for (int r = 0; r < 4; r++) {
                        float m = fmaxf(fmaxf(acc[i][0][r], acc[i][1][r]),
                                        fmaxf(acc[i][2][r], acc[i][3][r]));
                        m = fmaxf(m, __shfl_xor(m, 1, 64));
                        m = fmaxf(m, __shfl_xor(m, 2, 64));
                        m = fmaxf(m, __shfl_xor(m, 4, 64));
                        m = fmaxf(m, __shfl_xor(m, 8, 64));
                        runmax[i * 4 + r] = fmaxf(runmax[i * 4 + r], m);
                        float thr = runmax[i * 4 + r] - MARGIN_ACC;
                        int rl = wave * 32 + i * 16 + quad * 4 + r;
#pragma unroll
                        for (int j = 0; j < 4; j++) {
                            float d = acc[i][j][r];
                            if (d >= thr) {
                                int pos = atomicAdd(&lcnt[rl], 1);
                                if (pos < LSLOTS) {
                                    lcd[rl * LSLOTS + pos] = d;
                                    lci[rl * LSLOTS + pos] = cb0 + j * 16 + l16;
                                }
                            }
                        }
                    }
            }

            // end-of-iter: drain stage(it+1) + own LDS ops, publish slot.
            if (it < 30) {
                asm volatile("s_waitcnt vmcnt(2) lgkmcnt(0)" ::: "memory");
                block_barrier();
            } else if (it == 30) {
                asm volatile("s_waitcnt vmcnt(0) lgkmcnt(0)" ::: "memory");
                block_barrier();
            }                                  // it==31: nothing outstanding
        }
    }

    if (l16 == 0) {
#pragma unroll
        for (int i = 0; i < 2; i++)
#pragma unroll
            for (int r = 0; r < 4; r++)
                gmaxs[wave * 32 + i * 16 + quad * 4 + r] = runmax[i * 4 + r];
    }
    __syncthreads();

    // filter appends vs final row max (winner guaranteed in the superset).
    // [split][n] layout: each block writes a contiguous private range.
    if (tid < 128) {
        int n   = n0 + tid;
        int cnt = lcnt[tid]; if (cnt > LSLOTS) cnt = LSLOTS;
        float thrf = gmaxs[tid] - MARGIN_ACC;
        int base = (split * N_ROWS + n) * GSLOTS;
        int w = 0;
        for (int s = 0; s < cnt && w < GSLOTS; s++)
            if (lcd[tid * LSLOTS + s] >= thrf)
                cand_idx[base + w++] = lci[tid * LSLOTS + s];
        cand_cnt[split * N_ROWS + n] = w;
    }
}

// ---------------------------------------------------------------- kernel C
// Exact fp32 recheck (association identical to the passing version:
// sequential fmaf d=0..255, fmaf(-2,m,xn)+cn), lexicographic (dist,idx) min;
// then gather + z_q_st + rowloss. One wave per row.
__global__ __launch_bounds__(256) void vq_finalize(const float* __restrict__ z_e,
                                                   const float* __restrict__ cb,
                                                   const float* __restrict__ xnorm,
                                                   const float* __restrict__ cnorm,
                                                   const int* __restrict__ cand_cnt,
                                                   const int* __restrict__ cand_idx,
                                                   float* __restrict__ out_zq,
                                                   float* __restrict__ out_idx,
                                                   float* __restrict__ rowloss) {
    const int n    = blockIdx.x * 4 + (threadIdx.x >> 6);
    const int lane = threadIdx.x & 63;

    int myidx = -1;
    int t = 0;
#pragma unroll
    for (int s = 0; s < SPLITK; s++) {
        int c = cand_cnt[s * N_ROWS + n];
        if (lane >= t && lane < t + c)
            myidx = cand_idx[(s * N_ROWS + n) * GSLOTS + (lane - t)];
        t += c;
    }

    u64 key = ~0ULL;
    if (myidx >= 0) {
        const float* xr = z_e + (size_t)n * DIM;
        const float* cr = cb + (size_t)myidx * DIM;
        float acc = 0.0f;
#pragma unroll 8
        for (int d = 0; d < DIM; d++)
            acc = __builtin_fmaf(xr[d], cr[d], acc);
        float dist = __builtin_fmaf(-2.0f, acc, xnorm[n]) + cnorm[myidx];
        key = ((u64)__float_as_uint(dist) << 32) | (unsigned)myidx;
    }
#pragma unroll
    for (int off = 1; off < 64; off <<= 1)
        key = u64min(key, __shfl_xor(key, off, 64));

    int idx = (int)(unsigned)(key & 0xffffffffu);
    if (key == ~0ULL) idx = 0;  // unreachable safety

    float4 x = *(const float4*)(z_e + (size_t)n * DIM + lane * 4);
    float4 c = *(const float4*)(cb + (size_t)idx * DIM + lane * 4);
    float4 st;
    st.x = x.x + (c.x - x.x); st.y = x.y + (c.y - x.y);
    st.z = x.z + (c.z - x.z); st.w = x.w + (c.w - x.w);
    *(float4*)(out_zq + (size_t)n * DIM + lane * 4) = st;

    float d0 = x.x - c.x, d1 = x.y - c.y, d2 = x.z - c.z, d3 = x.w - c.w;
    float s2 = (d0 * d0 + d1 * d1) + (d2 * d2 + d3 * d3);
#pragma unroll
    for (int off = 1; off < 64; off <<= 1)
        s2 += __shfl_xor(s2, off, 64);
    if (lane == 0) {
        rowloss[n] = s2;
        out_idx[n] = (float)idx;
    }
}

// ---------------------------------------------------------------- kernel D
__global__ __launch_bounds__(256) void vq_loss(const float* __restrict__ rowloss,
                                               float* __restrict__ out_loss) {
    __shared__ double sd[256];
    double s = 0.0;
    for (int i = threadIdx.x; i < N_ROWS; i += 256) s += (double)rowloss[i];
    sd[threadIdx.x] = s;
    __syncthreads();
    for (int off = 128; off; off >>= 1) {
        if (threadIdx.x < off) sd[threadIdx.x] += sd[threadIdx.x + off];
        __syncthreads();
    }
    if (threadIdx.x == 0) {
        double mean = sd[0] / (double)((size_t)N_ROWS * DIM);
        out_loss[0] = (float)(1.25 * mean);
    }
}

// ---------------------------------------------------------------- launch
extern "C" void kernel_launch(void* const* d_in, const int* in_sizes, int n_in,
                              void* d_out, int out_size, void* d_ws, size_t ws_size,
                              hipStream_t stream) {
    const float* z_e = (const float*)d_in[0];
    const float* cb  = (const float*)d_in[1];

    float* out   = (float*)d_out;
    float* zq    = out;
    float* oidx  = out + (size_t)N_ROWS * DIM;
    float* oloss = oidx + N_ROWS;

    // ws layout (~12.6 MB):
    //   zb   bf16[8192*256]  4 MB
    //   cbb  bf16[8192*256]  4 MB
    //   xnorm/cnorm/rowloss  3*32 KB
    //   cand_cnt int[SPLITK*N_ROWS]        512 KB   ([split][n] layout)
    //   cand_idx int[SPLITK*N_ROWS*GSLOTS] 4 MB     ([split][n][slot])
    u16*   zb       = (u16*)d_ws;
    u16*   cbb      = zb + (size_t)N_ROWS * DIM;
    float* xnorm    = (float*)(cbb + (size_t)K_CODES * DIM);
    float* cnorm    = xnorm + N_ROWS;
    float* rowloss  = cnorm + K_CODES;
    int*   cand_cnt = (int*)(rowloss + N_ROWS);
    int*   cand_idx = cand_cnt + N_ROWS * SPLITK;

    vq_prep    <<<(N_ROWS + K_CODES) / 4, 256, 0, stream>>>(z_e, cb, zb, cbb, xnorm, cnorm);
    // grid (split, mtile): linear%8 == split%8 -> splits s and s+8 pinned to
    // one XCD; their 2x128KB bf16 codebook slices + zb rows stay L2-resident.
    vq_mfma    <<<dim3(SPLITK, N_ROWS / 128), 256, 0, stream>>>(zb, cbb, cand_cnt, cand_idx);
    vq_finalize<<<N_ROWS / 4, 256, 0, stream>>>(z_e, cb, xnorm, cnorm, cand_cnt, cand_idx, zq, oidx, rowloss);
    vq_loss    <<<1, 256, 0, stream>>>(rowloss, oloss);
}

// Round 9
// 175.595 us; speedup vs baseline: 1.5588x; 1.2083x over previous
//
#include <hip/hip_runtime.h>
#include <stdint.h>

#define N_ROWS  8192   // B*S = 4*2048
#define DIM     256
#define K_CODES 8192
#define SPLITK  8
#define KS      1024          // codes per split
#define NT      128           // codes per K-tile
#define LSLOTS  16            // per-row append slots in LDS
#define GSLOTS  8             // per-row-split survivor slots in ws (top-8 by dot)
// acc-space (dot) margin: covers dist-bucket/2 (1.5e-5) + 2*bf16 dot err max
// (~4.5e-5) + dropped cnorm/2 (1.9e-6). 1e-4 leaves ~1.6x slack.
#define MARGIN_ACC 1.0e-4f

typedef unsigned long long u64;
typedef unsigned short u16;
typedef short s16x8 __attribute__((ext_vector_type(8)));   // 8 bf16 = 4 VGPR
typedef float f32x4 __attribute__((ext_vector_type(4)));

__device__ __forceinline__ u64 u64min(u64 a, u64 b) { return a < b ? a : b; }

// float -> bf16 bits, round-to-nearest-even (no NaN inputs here)
__device__ __forceinline__ u16 f2bf(float f) {
    unsigned u = __float_as_uint(f);
    u += 0x7fffu + ((u >> 16) & 1u);
    return (u16)(u >> 16);
}

// async 16B global->LDS (dest = wave-uniform base + lane*16, HW-added)
__device__ __forceinline__ void gld16(void* lds, const void* g) {
    __builtin_amdgcn_global_load_lds(
        (const __attribute__((address_space(1))) unsigned int*)g,
        (__attribute__((address_space(3))) unsigned int*)lds, 16, 0, 0);
}

// Raw s_barrier with compiler memory fences on BOTH sides (naked builtin
// does not order memory at the compiler level).
__device__ __forceinline__ void block_barrier() {
    asm volatile("" ::: "memory");
    __builtin_amdgcn_s_barrier();
    asm volatile("" ::: "memory");
}

// ---------------------------------------------------------------- kernel A
// Fused: bf16 conversion of z_e & cb + row norms. One wave per row.
__global__ __launch_bounds__(256) void vq_prep(const float* __restrict__ z_e,
                                               const float* __restrict__ cb,
                                               u16* __restrict__ zb,
                                               u16* __restrict__ cbb,
                                               float* __restrict__ xnorm,
                                               float* __restrict__ cnorm) {
    int wid  = (blockIdx.x * 256 + threadIdx.x) >> 6;
    int lane = threadIdx.x & 63;
    const float* src; u16* d16; float* dn;
    if (wid < N_ROWS) { src = z_e + (size_t)wid * DIM; d16 = zb + (size_t)wid * DIM; dn = xnorm + wid; }
    else              { int k = wid - N_ROWS;
                        src = cb  + (size_t)k   * DIM; d16 = cbb + (size_t)k * DIM; dn = cnorm + k; }
    float4 v = *(const float4*)(src + lane * 4);
    ushort4 h;
    h.x = f2bf(v.x); h.y = f2bf(v.y); h.z = f2bf(v.z); h.w = f2bf(v.w);
    *(ushort4*)(d16 + lane * 4) = h;
    float s = (v.x * v.x + v.y * v.y) + (v.z * v.z + v.w * v.w);
#pragma unroll
    for (int off = 1; off < 64; off <<= 1)
        s += __shfl_xor(s, off, 64);
    if (lane == 0) *dn = s;
}

// ---------------------------------------------------------------- kernel B
// bf16 MFMA dot GEMM + per-row running MAX of dot (argmin dist == argmax dot)
// + margin-append. Block: 128 rows x 1024 codes (one split), 4 waves, each a
// 32-row slab owning ALL 128 codes of each tile.
//
// R9 = the best VERIFIED config (R2-round: 64us, passed) + R5 hardening:
//  * af[2][8] = 64 VGPR A-fragments loaded once (VGPR_Count 108, no spill).
//  * C staged into 3-deep ring of 16 KB chunks (128 codes x 64 dims, 128B-row
//    XOR swizzle, 2-way-free banking). 32 iters, each:
//      STAGE(it+2) -> 16x ds_read_b128 -> 32 MFMA
//      -> vmcnt(4) lgkmcnt(0) -> fenced barrier
//    vmcnt(4) drains stage(it+1) (FIFO; af retires under the first wait).
//  * Hardening (strictly conservative vs the R2-round pass): fenced barriers
//    + lgkmcnt(0) runtime drain of this wave's LDS reads before the barrier.
//  * Filter: top-GSLOTS survivors BY DOT (replace-min) + dots stored to ws
//    (cand_dot) so vq_finalize can margin-prefilter globally.
__global__ __launch_bounds__(256, 2) void vq_mfma(const u16* __restrict__ zb,
                                                  const u16* __restrict__ cbb,
                                                  int* __restrict__ cand_cnt,
                                                  int* __restrict__ cand_idx,
                                                  float* __restrict__ cand_dot) {
    __shared__ u16   Cs[3][128 * 64];   // 48 KB ring: 3 x (128 code-rows x 64 dims), swizzled
    __shared__ float lcd[128 * LSLOTS];
    __shared__ int   lci[128 * LSLOTS];
    __shared__ int   lcnt[128];
    __shared__ float gmaxs[128];

    const int tid   = threadIdx.x;
    const int lane  = tid & 63;
    const int wave  = tid >> 6;
    const int quad  = lane >> 4;
    const int l16   = lane & 15;
    const int split = blockIdx.x;
    const int n0    = blockIdx.y * 128;

    if (tid < 128) lcnt[tid] = 0;

    // staging lane constants: lane covers (row srow8 of 8-group, dest chunk schunk)
    const int srow8  = lane >> 3;
    const int schunk = lane & 7;
    const int ssw    = (schunk ^ srow8) * 8;   // swizzled source chunk offset (shorts)
    const u16* csrc  = cbb + (size_t)split * KS * DIM + (size_t)srow8 * DIM + ssw;

    // ---- A fragments in registers (issued FIRST: retire under the first
    // vmcnt(4) by FIFO order). af[i][s]: row n0+wave*32+i*16+l16,
    // dims s*32 + quad*8 .. +7   (s = kc*2+ks)
    s16x8 af[2][8];
#pragma unroll
    for (int i = 0; i < 2; i++) {
        const u16* p = zb + (size_t)(n0 + wave * 32 + i * 16 + l16) * DIM + quad * 8;
#pragma unroll
        for (int s = 0; s < 8; s++)
            af[i][s] = *(const s16x8*)(p + s * 32);
    }

    // stage chunk-iter s (code-tile s>>2, 64-dim chunk s&3) into Cs[bw]
    auto STAGE = [&](int s, int bw) {
        const u16* src = csrc + (size_t)(s >> 2) * (NT * DIM) + (s & 3) * 64;
#pragma unroll
        for (int t = 0; t < 4; t++) {
            int rg = wave * 4 + t;            // 8-code-row group, wave-uniform
            gld16(&Cs[bw][rg * 512], src + (size_t)rg * (8 * DIM));
        }
    };

    float runmax[8];
#pragma unroll
    for (int t = 0; t < 8; t++) runmax[t] = -3.0e38f;

    // prologue: fill ring slots 0,1; vmcnt(4) drains af(16)+stage0(4),
    // leaves stage1's 4 loads in flight.
    STAGE(0, 0);
    STAGE(1, 1);
    asm volatile("s_waitcnt vmcnt(4) lgkmcnt(0)" ::: "memory");
    block_barrier();

    int bufR = 0, bufW = 2;

    for (int kt = 0; kt < 8; kt++) {
        const int kbase = split * KS + kt * NT;
        f32x4 acc[2][8];
#pragma unroll
        for (int i = 0; i < 2; i++)
#pragma unroll
            for (int j = 0; j < 8; j++)
#pragma unroll
                for (int e = 0; e < 4; e++) acc[i][j][e] = 0.0f;

#pragma unroll
        for (int kc = 0; kc < 4; kc++) {     // 64-dim chunks, flat iter index
            const int it = (kt << 2) | kc;
            if (it < 30) STAGE(it + 2, bufW);     // 2-ahead prefetch

            const u16* cbuf = &Cs[bufR][0];       // staged(it); ready per barrier(it-1)
#pragma unroll
            for (int ks = 0; ks < 2; ks++) {
                s16x8 bfr[8];
#pragma unroll
                for (int j = 0; j < 8; j++)
                    bfr[j] = *(const s16x8*)&cbuf[(j * 16 + l16) * 64 +
                                                  (((ks << 2) | quad) ^ (l16 & 7)) * 8];
#pragma unroll
                for (int i = 0; i < 2; i++)
#pragma unroll
                    for (int j = 0; j < 8; j++)
                        acc[i][j] = __builtin_amdgcn_mfma_f32_16x16x32_bf16(
                            af[i][kc * 2 + ks], bfr[j], acc[i][j], 0, 0, 0);
            }

            // end-of-iter: drain stage(it+1) + this wave's LDS reads, then
            // fenced barrier => next iter's reads safe + ring overwrite safe.
            if (it < 30) {
                asm volatile("s_waitcnt vmcnt(4) lgkmcnt(0)" ::: "memory");
                block_barrier();
            } else if (it == 30) {
                asm volatile("s_waitcnt vmcnt(0) lgkmcnt(0)" ::: "memory");
                block_barrier();
            }                                      // it==31: nothing outstanding
            bufR = bufR == 2 ? 0 : bufR + 1;
            bufW = bufW == 2 ? 0 : bufW + 1;
        }

        // ---- epilogue: in-wave row max over 8 code-frags, runmax update,
        // margin appends. Row rl = wave*32 + i*16 + quad*4 + r (wave-owned).
#pragma unroll
        for (int i = 0; i < 2; i++)
#pragma unroll
            for (int r = 0; r < 4; r++) {
                float m = fmaxf(fmaxf(fmaxf(acc[i][0][r], acc[i][1][r]),
                                      fmaxf(acc[i][2][r], acc[i][3][r])),
                                fmaxf(fmaxf(acc[i][4][r], acc[i][5][r]),
                                      fmaxf(acc[i][6][r], acc[i][7][r])));
                m = fmaxf(m, __shfl_xor(m, 1, 64));
                m = fmaxf(m, __shfl_xor(m, 2, 64));
                m = fmaxf(m, __shfl_xor(m, 4, 64));
                m = fmaxf(m, __shfl_xor(m, 8, 64));
                runmax[i * 4 + r] = fmaxf(runmax[i * 4 + r], m);
                float thr = runmax[i * 4 + r] - MARGIN_ACC;
                int rl = wave * 32 + i * 16 + quad * 4 + r;
#pragma unroll
                for (int j = 0; j < 8; j++) {
                    float d = acc[i][j][r];
                    if (d >= thr) {
                        int pos = atomicAdd(&lcnt[rl], 1);
                        if (pos < LSLOTS) {
                            lcd[rl * LSLOTS + pos] = d;
                            lci[rl * LSLOTS + pos] = kbase + j * 16 + l16;
                        }
                    }
                }
            }
    }

    if (l16 == 0) {
#pragma unroll
        for (int i = 0; i < 2; i++)
#pragma unroll
            for (int r = 0; r < 4; r++)
                gmaxs[wave * 32 + i * 16 + quad * 4 + r] = runmax[i * 4 + r];
    }
    __syncthreads();

    // filter appends vs final row max; keep TOP-GSLOTS BY DOT (replace-min)
    // and store dots so finalize can margin-prefilter globally.
    // [split][n] layout: each block writes a contiguous private range.
    if (tid < 128) {
        int n   = n0 + tid;
        int cnt = lcnt[tid]; if (cnt > LSLOTS) cnt = LSLOTS;
        float thrf = gmaxs[tid] - MARGIN_ACC;
        float bd[GSLOTS]; int bi[GSLOTS];
        int w = 0;
        for (int s = 0; s < cnt; s++) {
            float d = lcd[tid * LSLOTS + s];
            if (d < thrf) continue;
            if (w < GSLOTS) { bd[w] = d; bi[w] = lci[tid * LSLOTS + s]; w++; }
            else {
                int mn = 0;
#pragma unroll
                for (int k = 1; k < GSLOTS; k++) if (bd[k] < bd[mn]) mn = k;
                if (d > bd[mn]) { bd[mn] = d; bi[mn] = lci[tid * LSLOTS + s]; }
            }
        }
        int base = (split * N_ROWS + n) * GSLOTS;
        for (int k = 0; k < w; k++) {
            cand_idx[base + k] = bi[k];
            cand_dot[base + k] = bd[k];
        }
        cand_cnt[split * N_ROWS + n] = w;
    }
}

// ---------------------------------------------------------------- kernel C
// Gather candidates WITH their bf16 acc-dots; global margin prefilter
// (dot >= max_dot - MARGIN_ACC retains the true winner by the same error
// bound that justifies the per-split filter); then exact fp32 recheck of
// the ~1-2 survivors with numerics BIT-IDENTICAL to the passing version
// (sequential fmaf d=0..255, fmaf(-2,m,xn)+cn, lexicographic (dist,idx)
// min); then gather + z_q_st + rowloss. One wave per row.
__global__ __launch_bounds__(256) void vq_finalize(const float* __restrict__ z_e,
                                                   const float* __restrict__ cb,
                                                   const float* __restrict__ xnorm,
                                                   const float* __restrict__ cnorm,
                                                   const int* __restrict__ cand_cnt,
                                                   const int* __restrict__ cand_idx,
                                                   const float* __restrict__ cand_dot,
                                                   float* __restrict__ out_zq,
                                                   float* __restrict__ out_idx,
                                                   float* __restrict__ rowloss) {
    const int n    = blockIdx.x * 4 + (threadIdx.x >> 6);
    const int lane = threadIdx.x & 63;

    int   myidx = -1;
    float mydot = -3.0e38f;
    int t = 0;
#pragma unroll
    for (int s = 0; s < SPLITK; s++) {
        int c = cand_cnt[s * N_ROWS + n];
        if (lane >= t && lane < t + c) {
            myidx = cand_idx[(s * N_ROWS + n) * GSLOTS + (lane - t)];
            mydot = cand_dot[(s * N_ROWS + n) * GSLOTS + (lane - t)];
        }
        t += c;
    }

    // global (row-wide) max of stored bf16 dots
    float mg = mydot;
#pragma unroll
    for (int off = 1; off < 64; off <<= 1)
        mg = fmaxf(mg, __shfl_xor(mg, off, 64));

    u64 key = ~0ULL;
    if (myidx >= 0 && mydot >= mg - MARGIN_ACC) {   // ~1-2 lanes survive
        const float* xr = z_e + (size_t)n * DIM;
        const float* cr = cb + (size_t)myidx * DIM;
        float acc = 0.0f;
#pragma unroll 8
        for (int d = 0; d < DIM; d++)
            acc = __builtin_fmaf(xr[d], cr[d], acc);
        float dist = __builtin_fmaf(-2.0f, acc, xnorm[n]) + cnorm[myidx];
        key = ((u64)__float_as_uint(dist) << 32) | (unsigned)myidx;
    }
#pragma unroll
    for (int off = 1; off < 64; off <<= 1)
        key = u64min(key, __shfl_xor(key, off, 64));

    int idx = (int)(unsigned)(key & 0xffffffffu);
    if (key == ~0ULL) idx = 0;  // unreachable safety

    float4 x = *(const float4*)(z_e + (size_t)n * DIM + lane * 4);
    float4 c = *(const float4*)(cb + (size_t)idx * DIM + lane * 4);
    float4 st;
    st.x = x.x + (c.x - x.x); st.y = x.y + (c.y - x.y);
    st.z = x.z + (c.z - x.z); st.w = x.w + (c.w - x.w);
    *(float4*)(out_zq + (size_t)n * DIM + lane * 4) = st;

    float d0 = x.x - c.x, d1 = x.y - c.y, d2 = x.z - c.z, d3 = x.w - c.w;
    float s2 = (d0 * d0 + d1 * d1) + (d2 * d2 + d3 * d3);
#pragma unroll
    for (int off = 1; off < 64; off <<= 1)
        s2 += __shfl_xor(s2, off, 64);
    if (lane == 0) {
        rowloss[n] = s2;
        out_idx[n] = (float)idx;
    }
}

// ---------------------------------------------------------------- kernel D
__global__ __launch_bounds__(256) void vq_loss(const float* __restrict__ rowloss,
                                               float* __restrict__ out_loss) {
    __shared__ double sd[256];
    double s = 0.0;
    for (int i = threadIdx.x; i < N_ROWS; i += 256) s += (double)rowloss[i];
    sd[threadIdx.x] = s;
    __syncthreads();
    for (int off = 128; off; off >>= 1) {
        if (threadIdx.x < off) sd[threadIdx.x] += sd[threadIdx.x + off];
        __syncthreads();
    }
    if (threadIdx.x == 0) {
        double mean = sd[0] / (double)((size_t)N_ROWS * DIM);
        out_loss[0] = (float)(1.25 * mean);
    }
}

// ---------------------------------------------------------------- launch
extern "C" void kernel_launch(void* const* d_in, const int* in_sizes, int n_in,
                              void* d_out, int out_size, void* d_ws, size_t ws_size,
                              hipStream_t stream) {
    const float* z_e = (const float*)d_in[0];
    const float* cb  = (const float*)d_in[1];

    float* out   = (float*)d_out;
    float* zq    = out;
    float* oidx  = out + (size_t)N_ROWS * DIM;
    float* oloss = oidx + N_ROWS;

    // ws layout (~12.3 MB):
    //   zb   bf16[8192*256]  4 MB
    //   cbb  bf16[8192*256]  4 MB
    //   xnorm/cnorm/rowloss  3*32 KB
    //   cand_cnt int[SPLITK*N_ROWS]          256 KB  ([split][n] layout)
    //   cand_idx int[SPLITK*N_ROWS*GSLOTS]   2 MB
    //   cand_dot f32[SPLITK*N_ROWS*GSLOTS]   2 MB
    u16*   zb       = (u16*)d_ws;
    u16*   cbb      = zb + (size_t)N_ROWS * DIM;
    float* xnorm    = (float*)(cbb + (size_t)K_CODES * DIM);
    float* cnorm    = xnorm + N_ROWS;
    float* rowloss  = cnorm + K_CODES;
    int*   cand_cnt = (int*)(rowloss + N_ROWS);
    int*   cand_idx = cand_cnt + N_ROWS * SPLITK;
    float* cand_dot = (float*)(cand_idx + (size_t)N_ROWS * SPLITK * GSLOTS);

    vq_prep    <<<(N_ROWS + K_CODES) / 4, 256, 0, stream>>>(z_e, cb, zb, cbb, xnorm, cnorm);
    // grid (split, mtile): linear%8 == split -> each split pinned to one XCD;
    // its 0.5MB bf16 codebook slice + zb rows stay L2-resident.
    vq_mfma    <<<dim3(SPLITK, N_ROWS / 128), 256, 0, stream>>>(zb, cbb, cand_cnt, cand_idx, cand_dot);
    vq_finalize<<<N_ROWS / 4, 256, 0, stream>>>(z_e, cb, xnorm, cnorm, cand_cnt, cand_idx, cand_dot, zq, oidx, rowloss);
    vq_loss    <<<1, 256, 0, stream>>>(rowloss, oloss);
}

// Round 10
// 172.184 us; speedup vs baseline: 1.5897x; 1.0198x over previous
//
#include <hip/hip_runtime.h>
#include <stdint.h>

#define N_ROWS  8192   // B*S = 4*2048
#define DIM     256
#define K_CODES 8192
#define SPLITK  8
#define KS      1024          // codes per split
#define NT      128           // codes per K-tile
#define LSLOTS  16            // per-row append slots in LDS
#define GSLOTS  8             // per-row-split survivor slots in ws (top-8 by dot)
// acc-space (dot) margin: covers dist-bucket/2 (1.5e-5) + 2*bf16 dot err max
// (~4.5e-5) + dropped cnorm/2 (1.9e-6). 1e-4 leaves ~1.6x slack.
#define MARGIN_ACC 1.0e-4f

typedef unsigned long long u64;
typedef unsigned short u16;
typedef short s16x8 __attribute__((ext_vector_type(8)));   // 8 bf16 = 4 VGPR
typedef float f32x4 __attribute__((ext_vector_type(4)));

__device__ __forceinline__ u64 u64min(u64 a, u64 b) { return a < b ? a : b; }

// float -> bf16 bits, round-to-nearest-even (no NaN inputs here)
__device__ __forceinline__ u16 f2bf(float f) {
    unsigned u = __float_as_uint(f);
    u += 0x7fffu + ((u >> 16) & 1u);
    return (u16)(u >> 16);
}

// async 16B global->LDS (dest = wave-uniform base + lane*16, HW-added)
__device__ __forceinline__ void gld16(void* lds, const void* g) {
    __builtin_amdgcn_global_load_lds(
        (const __attribute__((address_space(1))) unsigned int*)g,
        (__attribute__((address_space(3))) unsigned int*)lds, 16, 0, 0);
}

// Raw s_barrier with compiler memory fences on BOTH sides (naked builtin
// does not order memory at the compiler level).
__device__ __forceinline__ void block_barrier() {
    asm volatile("" ::: "memory");
    __builtin_amdgcn_s_barrier();
    asm volatile("" ::: "memory");
}

// ---------------------------------------------------------------- kernel A
// Fused: bf16 conversion of z_e & cb + row norms. One wave per row.
__global__ __launch_bounds__(256) void vq_prep(const float* __restrict__ z_e,
                                               const float* __restrict__ cb,
                                               u16* __restrict__ zb,
                                               u16* __restrict__ cbb,
                                               float* __restrict__ xnorm,
                                               float* __restrict__ cnorm) {
    int wid  = (blockIdx.x * 256 + threadIdx.x) >> 6;
    int lane = threadIdx.x & 63;
    const float* src; u16* d16; float* dn;
    if (wid < N_ROWS) { src = z_e + (size_t)wid * DIM; d16 = zb + (size_t)wid * DIM; dn = xnorm + wid; }
    else              { int k = wid - N_ROWS;
                        src = cb  + (size_t)k   * DIM; d16 = cbb + (size_t)k * DIM; dn = cnorm + k; }
    float4 v = *(const float4*)(src + lane * 4);
    ushort4 h;
    h.x = f2bf(v.x); h.y = f2bf(v.y); h.z = f2bf(v.z); h.w = f2bf(v.w);
    *(ushort4*)(d16 + lane * 4) = h;
    float s = (v.x * v.x + v.y * v.y) + (v.z * v.z + v.w * v.w);
#pragma unroll
    for (int off = 1; off < 64; off <<= 1)
        s += __shfl_xor(s, off, 64);
    if (lane == 0) *dn = s;
}

// ---------------------------------------------------------------- kernel B
// bf16 MFMA dot GEMM + per-row running MAX of dot (argmin dist == argmax dot)
// + margin-append. Block: 128 rows x 1024 codes (one split), 4 waves, each a
// 32-row slab owning ALL 128 codes of each tile.
//
// R10 = R9's verified 32-MFMA-per-barrier phase at 3 blocks/CU:
//  * Ring 3 slots -> 2 slots (32 KB): LDS 66.5 -> 50.2 KB < 53.3 KB, so 3
//    blocks/CU (12 waves/CU) become resident. R9's 2-block residency left
//    only one other block to cover each barrier drain (MfmaUtil 19%).
//    R5/R7 had 3-block LDS but confounded with half-size phases; this round
//    changes ONLY ring depth vs R9.
//  * 2-slot schedule (issue-early / drain-late):
//      barrier -> STAGE(it+1) [slot whose readers drained last phase]
//      -> 16x ds_read_b128 + 32 MFMA on slot it&1 [-> epilogue at kt end]
//      -> vmcnt(0) lgkmcnt(0) -> fenced barrier
//    Stage cover = one full compute phase (~600+ cyc > L2 ~300 cyc), so the
//    vmcnt(0) drain is short. Race-freedom: writers only touch the slot
//    whose readers drained (lgkmcnt(0)) before the previous barrier; all
//    barriers are compiler-fenced (R5 hardening).
//  * af[2][8] A-fragments loaded once (VGPR ~108, no spill at (256,2)).
//  * Filter: top-GSLOTS survivors BY DOT (replace-min) + dots stored to ws
//    (cand_dot) so vq_finalize can margin-prefilter globally (R9, verified).
__global__ __launch_bounds__(256, 2) void vq_mfma(const u16* __restrict__ zb,
                                                  const u16* __restrict__ cbb,
                                                  int* __restrict__ cand_cnt,
                                                  int* __restrict__ cand_idx,
                                                  float* __restrict__ cand_dot) {
    __shared__ u16   Cs[2][128 * 64];   // 32 KB ring: 2 x (128 code-rows x 64 dims), swizzled
    __shared__ float lcd[128 * LSLOTS];
    __shared__ int   lci[128 * LSLOTS];
    __shared__ int   lcnt[128];
    __shared__ float gmaxs[128];

    const int tid   = threadIdx.x;
    const int lane  = tid & 63;
    const int wave  = tid >> 6;
    const int quad  = lane >> 4;
    const int l16   = lane & 15;
    const int split = blockIdx.x;
    const int n0    = blockIdx.y * 128;

    if (tid < 128) lcnt[tid] = 0;

    // staging lane constants: lane covers (row srow8 of 8-group, dest chunk schunk)
    const int srow8  = lane >> 3;
    const int schunk = lane & 7;
    const int ssw    = (schunk ^ srow8) * 8;   // swizzled source chunk offset (shorts)
    const u16* csrc  = cbb + (size_t)split * KS * DIM + (size_t)srow8 * DIM + ssw;

    // ---- A fragments in registers (issued FIRST: retire under the first
    // vmcnt(0)). af[i][s]: row n0+wave*32+i*16+l16, dims s*32 + quad*8 .. +7
    s16x8 af[2][8];
#pragma unroll
    for (int i = 0; i < 2; i++) {
        const u16* p = zb + (size_t)(n0 + wave * 32 + i * 16 + l16) * DIM + quad * 8;
#pragma unroll
        for (int s = 0; s < 8; s++)
            af[i][s] = *(const s16x8*)(p + s * 32);
    }

    // stage chunk-iter s (code-tile s>>2, 64-dim chunk s&3) into Cs[slot]
    auto STAGE = [&](int s, int slot) {
        const u16* src = csrc + (size_t)(s >> 2) * (NT * DIM) + (s & 3) * 64;
#pragma unroll
        for (int t = 0; t < 4; t++) {
            int rg = wave * 4 + t;            // 8-code-row group, wave-uniform
            gld16(&Cs[slot][rg * 512], src + (size_t)rg * (8 * DIM));
        }
    };

    float runmax[8];
#pragma unroll
    for (int t = 0; t < 8; t++) runmax[t] = -3.0e38f;

    // prologue: stage(0) into slot 0; drain af(16)+stage0(16); publish.
    STAGE(0, 0);
    asm volatile("s_waitcnt vmcnt(0) lgkmcnt(0)" ::: "memory");
    block_barrier();

    for (int kt = 0; kt < 8; kt++) {
        const int kbase = split * KS + kt * NT;
        f32x4 acc[2][8];
#pragma unroll
        for (int i = 0; i < 2; i++)
#pragma unroll
            for (int j = 0; j < 8; j++)
#pragma unroll
                for (int e = 0; e < 4; e++) acc[i][j][e] = 0.0f;

#pragma unroll
        for (int kc = 0; kc < 4; kc++) {     // 64-dim chunks, flat iter index
            const int it = (kt << 2) | kc;
            // issue next-chunk stage FIRST: it writes slot (it+1)&1, whose
            // readers (phase it-1) drained before the last barrier.
            if (it < 31) STAGE(it + 1, (it + 1) & 1);

            const u16* cbuf = &Cs[it & 1][0];    // staged(it); ready per barrier(it-1)
#pragma unroll
            for (int ks = 0; ks < 2; ks++) {
                s16x8 bfr[8];
#pragma unroll
                for (int j = 0; j < 8; j++)
                    bfr[j] = *(const s16x8*)&cbuf[(j * 16 + l16) * 64 +
                                                  (((ks << 2) | quad) ^ (l16 & 7)) * 8];
#pragma unroll
                for (int i = 0; i < 2; i++)
#pragma unroll
                    for (int j = 0; j < 8; j++)
                        acc[i][j] = __builtin_amdgcn_mfma_f32_16x16x32_bf16(
                            af[i][kc * 2 + ks], bfr[j], acc[i][j], 0, 0, 0);
            }

            // drain stage(it+1) (had a full compute phase of cover) + this
            // wave's LDS reads; fenced barrier publishes slot (it+1)&1.
            if (it < 31) {
                asm volatile("s_waitcnt vmcnt(0) lgkmcnt(0)" ::: "memory");
                block_barrier();
            }                                    // it==31: nothing outstanding
        }

        // ---- epilogue: in-wave row max over 8 code-frags, runmax update,
        // margin appends. Row rl = wave*32 + i*16 + quad*4 + r (wave-owned;
        // lcd/lci/lcnt never restaged -> no cross-phase race).
#pragma unroll
        for (int i = 0; i < 2; i++)
#pragma unroll
            for (int r = 0; r < 4; r++) {
                float m = fmaxf(fmaxf(fmaxf(acc[i][0][r], acc[i][1][r]),
                                      fmaxf(acc[i][2][r], acc[i][3][r])),
                                fmaxf(fmaxf(acc[i][4][r], acc[i][5][r]),
                                      fmaxf(acc[i][6][r], acc[i][7][r])));
                m = fmaxf(m, __shfl_xor(m, 1, 64));
                m = fmaxf(m, __shfl_xor(m, 2, 64));
                m = fmaxf(m, __shfl_xor(m, 4, 64));
                m = fmaxf(m, __shfl_xor(m, 8, 64));
                runmax[i * 4 + r] = fmaxf(runmax[i * 4 + r], m);
                float thr = runmax[i * 4 + r] - MARGIN_ACC;
                int rl = wave * 32 + i * 16 + quad * 4 + r;
#pragma unroll
                for (int j = 0; j < 8; j++) {
                    float d = acc[i][j][r];
                    if (d >= thr) {
                        int pos = atomicAdd(&lcnt[rl], 1);
                        if (pos < LSLOTS) {
                            lcd[rl * LSLOTS + pos] = d;
                            lci[rl * LSLOTS + pos] = kbase + j * 16 + l16;
                        }
                    }
                }
            }
    }

    if (l16 == 0) {
#pragma unroll
        for (int i = 0; i < 2; i++)
#pragma unroll
            for (int r = 0; r < 4; r++)
                gmaxs[wave * 32 + i * 16 + quad * 4 + r] = runmax[i * 4 + r];
    }
    __syncthreads();

    // filter appends vs final row max; keep TOP-GSLOTS BY DOT (replace-min)
    // and store dots so finalize can margin-prefilter globally.
    // [split][n] layout: each block writes a contiguous private range.
    if (tid < 128) {
        int n   = n0 + tid;
        int cnt = lcnt[tid]; if (cnt > LSLOTS) cnt = LSLOTS;
        float thrf = gmaxs[tid] - MARGIN_ACC;
        float bd[GSLOTS]; int bi[GSLOTS];
        int w = 0;
        for (int s = 0; s < cnt; s++) {
            float d = lcd[tid * LSLOTS + s];
            if (d < thrf) continue;
            if (w < GSLOTS) { bd[w] = d; bi[w] = lci[tid * LSLOTS + s]; w++; }
            else {
                int mn = 0;
#pragma unroll
                for (int k = 1; k < GSLOTS; k++) if (bd[k] < bd[mn]) mn = k;
                if (d > bd[mn]) { bd[mn] = d; bi[mn] = lci[tid * LSLOTS + s]; }
            }
        }
        int base = (split * N_ROWS + n) * GSLOTS;
        for (int k = 0; k < w; k++) {
            cand_idx[base + k] = bi[k];
            cand_dot[base + k] = bd[k];
        }
        cand_cnt[split * N_ROWS + n] = w;
    }
}

// ---------------------------------------------------------------- kernel C
// Gather candidates WITH their bf16 acc-dots; global margin prefilter
// (dot >= max_dot - MARGIN_ACC retains the true winner by the same error
// bound that justifies the per-split filter); then exact fp32 recheck of
// the ~1-2 survivors with numerics BIT-IDENTICAL to the passing version
// (sequential fmaf d=0..255, fmaf(-2,m,xn)+cn, lexicographic (dist,idx)
// min); then gather + z_q_st + rowloss. One wave per row.
__global__ __launch_bounds__(256) void vq_finalize(const float* __restrict__ z_e,
                                                   const float* __restrict__ cb,
                                                   const float* __restrict__ xnorm,
                                                   const float* __restrict__ cnorm,
                                                   const int* __restrict__ cand_cnt,
                                                   const int* __restrict__ cand_idx,
                                                   const float* __restrict__ cand_dot,
                                                   float* __restrict__ out_zq,
                                                   float* __restrict__ out_idx,
                                                   float* __restrict__ rowloss) {
    const int n    = blockIdx.x * 4 + (threadIdx.x >> 6);
    const int lane = threadIdx.x & 63;

    int   myidx = -1;
    float mydot = -3.0e38f;
    int t = 0;
#pragma unroll
    for (int s = 0; s < SPLITK; s++) {
        int c = cand_cnt[s * N_ROWS + n];
        if (lane >= t && lane < t + c) {
            myidx = cand_idx[(s * N_ROWS + n) * GSLOTS + (lane - t)];
            mydot = cand_dot[(s * N_ROWS + n) * GSLOTS + (lane - t)];
        }
        t += c;
    }

    // global (row-wide) max of stored bf16 dots
    float mg = mydot;
#pragma unroll
    for (int off = 1; off < 64; off <<= 1)
        mg = fmaxf(mg, __shfl_xor(mg, off, 64));

    u64 key = ~0ULL;
    if (myidx >= 0 && mydot >= mg - MARGIN_ACC) {   // ~1-2 lanes survive
        const float* xr = z_e + (size_t)n * DIM;
        const float* cr = cb + (size_t)myidx * DIM;
        float acc = 0.0f;
#pragma unroll 8
        for (int d = 0; d < DIM; d++)
            acc = __builtin_fmaf(xr[d], cr[d], acc);
        float dist = __builtin_fmaf(-2.0f, acc, xnorm[n]) + cnorm[myidx];
        key = ((u64)__float_as_uint(dist) << 32) | (unsigned)myidx;
    }
#pragma unroll
    for (int off = 1; off < 64; off <<= 1)
        key = u64min(key, __shfl_xor(key, off, 64));

    int idx = (int)(unsigned)(key & 0xffffffffu);
    if (key == ~0ULL) idx = 0;  // unreachable safety

    float4 x = *(const float4*)(z_e + (size_t)n * DIM + lane * 4);
    float4 c = *(const float4*)(cb + (size_t)idx * DIM + lane * 4);
    float4 st;
    st.x = x.x + (c.x - x.x); st.y = x.y + (c.y - x.y);
    st.z = x.z + (c.z - x.z); st.w = x.w + (c.w - x.w);
    *(float4*)(out_zq + (size_t)n * DIM + lane * 4) = st;

    float d0 = x.x - c.x, d1 = x.y - c.y, d2 = x.z - c.z, d3 = x.w - c.w;
    float s2 = (d0 * d0 + d1 * d1) + (d2 * d2 + d3 * d3);
#pragma unroll
    for (int off = 1; off < 64; off <<= 1)
        s2 += __shfl_xor(s2, off, 64);
    if (lane == 0) {
        rowloss[n] = s2;
        out_idx[n] = (float)idx;
    }
}

// ---------------------------------------------------------------- kernel D
__global__ __launch_bounds__(256) void vq_loss(const float* __restrict__ rowloss,
                                               float* __restrict__ out_loss) {
    __shared__ double sd[256];
    double s = 0.0;
    for (int i = threadIdx.x; i < N_ROWS; i += 256) s += (double)rowloss[i];
    sd[threadIdx.x] = s;
    __syncthreads();
    for (int off = 128; off; off >>= 1) {
        if (threadIdx.x < off) sd[threadIdx.x] += sd[threadIdx.x + off];
        __syncthreads();
    }
    if (threadIdx.x == 0) {
        double mean = sd[0] / (double)((size_t)N_ROWS * DIM);
        out_loss[0] = (float)(1.25 * mean);
    }
}

// ---------------------------------------------------------------- launch
extern "C" void kernel_launch(void* const* d_in, const int* in_sizes, int n_in,
                              void* d_out, int out_size, void* d_ws, size_t ws_size,
                              hipStream_t stream) {
    const float* z_e = (const float*)d_in[0];
    const float* cb  = (const float*)d_in[1];

    float* out   = (float*)d_out;
    float* zq    = out;
    float* oidx  = out + (size_t)N_ROWS * DIM;
    float* oloss = oidx + N_ROWS;

    // ws layout (~12.3 MB):
    //   zb   bf16[8192*256]  4 MB
    //   cbb  bf16[8192*256]  4 MB
    //   xnorm/cnorm/rowloss  3*32 KB
    //   cand_cnt int[SPLITK*N_ROWS]          256 KB  ([split][n] layout)
    //   cand_idx int[SPLITK*N_ROWS*GSLOTS]   2 MB
    //   cand_dot f32[SPLITK*N_ROWS*GSLOTS]   2 MB
    u16*   zb       = (u16*)d_ws;
    u16*   cbb      = zb + (size_t)N_ROWS * DIM;
    float* xnorm    = (float*)(cbb + (size_t)K_CODES * DIM);
    float* cnorm    = xnorm + N_ROWS;
    float* rowloss  = cnorm + K_CODES;
    int*   cand_cnt = (int*)(rowloss + N_ROWS);
    int*   cand_idx = cand_cnt + N_ROWS * SPLITK;
    float* cand_dot = (float*)(cand_idx + (size_t)N_ROWS * SPLITK * GSLOTS);

    vq_prep    <<<(N_ROWS + K_CODES) / 4, 256, 0, stream>>>(z_e, cb, zb, cbb, xnorm, cnorm);
    // grid (split, mtile): linear%8 == split -> each split pinned to one XCD;
    // its 0.5MB bf16 codebook slice + zb rows stay L2-resident.
    vq_mfma    <<<dim3(SPLITK, N_ROWS / 128), 256, 0, stream>>>(zb, cbb, cand_cnt, cand_idx, cand_dot);
    vq_finalize<<<N_ROWS / 4, 256, 0, stream>>>(z_e, cb, xnorm, cnorm, cand_cnt, cand_idx, cand_dot, zq, oidx, rowloss);
    vq_loss    <<<1, 256, 0, stream>>>(rowloss, oloss);
}